// Round 7
// baseline (59.424 us; speedup 1.0000x reference)
//
#include <hip/hip_runtime.h>
#include <stdint.h>

#define LMAX 8
#define KCH 32
#define NC  64
#define TT  2048
#define LN2D 0.6931471805599453
#define NEGE (-(1<<28))

struct __align__(16) PK { unsigned long long key; float logp; int len; };

__device__ __forceinline__ int fexp(float m) { return ((__float_as_int(m) >> 23) & 0xFF) - 127; }
__device__ __forceinline__ int fexpbits(float m) { return (__float_as_int(m) >> 23) & 0xFF; }
__device__ __forceinline__ float p2(int e) { return __int_as_float((e + 127) << 23); }
__device__ __forceinline__ float p2c(int e) { return (e < -126) ? 0.f : p2(e); }

// K1: pack pieces into 64-bit keys, pack sequence windows, zero M.
__global__ void k_prep(const int* __restrict__ seq, const int* __restrict__ pieces,
                       const int* __restrict__ plens, const float* __restrict__ logp,
                       PK* __restrict__ pk, unsigned long long* __restrict__ w64,
                       float* __restrict__ M, int T, int V) {
  int idx = blockIdx.x * blockDim.x + threadIdx.x;
  if (idx < V) {
    const int* pr = pieces + idx * LMAX;
    int len = plens[idx];
    unsigned long long key = 0ull;
    #pragma unroll
    for (int l = 0; l < LMAX; ++l) {
      unsigned long long b = (unsigned long long)(pr[l] & 0xFF);
      if (l < len) key |= b << (8 * l);
    }
    PK o; o.key = key; o.logp = logp[idx]; o.len = len;
    pk[idx] = o;
  } else if (idx < V + T) {
    int t = idx - V;
    unsigned long long w = 0ull;
    #pragma unroll
    for (int l = 0; l < LMAX; ++l) {
      int pos = t + l;
      unsigned long long b = (pos < T) ? (unsigned long long)(seq[pos] & 0xFF) : 0xFFull;
      w |= b << (8 * l);
    }
    w64[t] = w;
  } else if (idx < V + T + T * LMAX) {
    M[idx - V - T] = 0.f;
  }
}

// K2: M[t][len-1] += p_v for every matching (t,v).
__global__ void k_match(const PK* __restrict__ pk, const unsigned long long* __restrict__ w64,
                        float* __restrict__ M, int T, int V, int tPer) {
  int v = blockIdx.x * blockDim.x + threadIdx.x;
  PK p = pk[v];
  unsigned long long mask = (p.len >= 8) ? ~0ull : ((1ull << (8 * p.len)) - 1ull);
  unsigned long long key = p.key;
  int t0 = blockIdx.y * tPer;
  float prob = -1.f;
  for (int t = t0; t < t0 + tPer; ++t) {
    unsigned long long w = w64[t];
    if (((w ^ key) & mask) == 0ull) {
      if (prob < 0.f) prob = expf(p.logp);
      atomicAdd(&M[t * LMAX + (p.len - 1)], prob);
    }
  }
}

// K3a: per-(dir,chunk,basis-col) chunk transfer-matrix columns.
// 16 blocks x 64 threads (8 tasks/block x 8 basis lanes). bounds(64,1) ->
// full VGPR budget, no spills. Rolled kg loop, 1-row-ahead prefetch.
__global__ __launch_bounds__(64, 1) void k_chunks(const float* __restrict__ M,
        float* __restrict__ Wt, int* __restrict__ EWc) {
  int gtid = blockIdx.x * 64 + threadIdx.x;    // 0..1023
  int task = gtid >> 3, b = gtid & 7;
  int dir = task >> 6, c = task & 63;
  int base = c * KCH;
  const float4* Mv = (const float4*)M;
  float v[8];
  #pragma unroll
  for (int i = 0; i < 8; ++i) v[i] = (i == b) ? 1.f : 0.f;
  int ec = 0;
  if (dir == 0) {          // alpha push-form
    float4 ra = Mv[base * 2], rb = Mv[base * 2 + 1];
    for (int kg = 0; kg < 4; ++kg) {
      #pragma unroll
      for (int kk = 0; kk < 8; ++kk) {
        int k = kg * 8 + kk;
        float4 c0 = ra, c1 = rb;
        int nk = (k + 1 < KCH) ? k + 1 : KCH - 1;
        ra = Mv[(base + nk) * 2]; rb = Mv[(base + nk) * 2 + 1];
        float a_ = v[kk & 7];
        v[(kk + 1) & 7] = fmaf(a_, c0.x, v[(kk + 1) & 7]);
        v[(kk + 2) & 7] = fmaf(a_, c0.y, v[(kk + 2) & 7]);
        v[(kk + 3) & 7] = fmaf(a_, c0.z, v[(kk + 3) & 7]);
        v[(kk + 4) & 7] = fmaf(a_, c0.w, v[(kk + 4) & 7]);
        v[(kk + 5) & 7] = fmaf(a_, c1.x, v[(kk + 5) & 7]);
        v[(kk + 6) & 7] = fmaf(a_, c1.y, v[(kk + 6) & 7]);
        v[(kk + 7) & 7] = fmaf(a_, c1.z, v[(kk + 7) & 7]);
        v[kk & 7]       = a_ * c1.w;
        if (kk == 3 || kk == 7) {
          float mx = 0.f;
          #pragma unroll
          for (int i = 0; i < 8; ++i) mx = fmaxf(mx, v[i]);
          if (fexpbits(mx) != 0) {
            int e = fexp(mx); float sc = p2(-e);
            #pragma unroll
            for (int i = 0; i < 8; ++i) v[i] *= sc;
            ec += e;
          }
        }
      }
    }
  } else {                 // beta window-form
    float4 ra = Mv[(base + KCH - 1) * 2], rb = Mv[(base + KCH - 1) * 2 + 1];
    for (int kg = 0; kg < 4; ++kg) {
      #pragma unroll
      for (int kk = 0; kk < 8; ++kk) {
        int k = kg * 8 + kk;
        float4 c0 = ra, c1 = rb;
        int nk = (k + 1 < KCH) ? k + 1 : KCH - 1;
        int nt = base + KCH - 1 - nk;
        ra = Mv[nt * 2]; rb = Mv[nt * 2 + 1];
        float nb =      c0.x * v[(8  - kk) & 7];
        nb = fmaf(c0.y, v[(9  - kk) & 7], nb);
        nb = fmaf(c0.z, v[(10 - kk) & 7], nb);
        nb = fmaf(c0.w, v[(11 - kk) & 7], nb);
        nb = fmaf(c1.x, v[(12 - kk) & 7], nb);
        nb = fmaf(c1.y, v[(13 - kk) & 7], nb);
        nb = fmaf(c1.z, v[(14 - kk) & 7], nb);
        nb = fmaf(c1.w, v[(15 - kk) & 7], nb);
        v[(7 - kk) & 7] = nb;
        if (kk == 3 || kk == 7) {
          float mx = 0.f;
          #pragma unroll
          for (int i = 0; i < 8; ++i) mx = fmaxf(mx, v[i]);
          if (fexpbits(mx) != 0) {
            int e = fexp(mx); float sc = p2(-e);
            #pragma unroll
            for (int i = 0; i < 8; ++i) v[i] *= sc;
            ec += e;
          }
        }
      }
    }
  }
  float mx = 0.f;
  #pragma unroll
  for (int i = 0; i < 8; ++i) mx = fmaxf(mx, v[i]);
  int ltask = dir * 64 + (dir ? 63 - c : c);   // logical order for combine
  float* wp = Wt + ltask * 64;
  if (fexpbits(mx) == 0) {
    #pragma unroll
    for (int i = 0; i < 8; ++i) wp[b * 8 + i] = 0.f;
    EWc[ltask * 8 + b] = NEGE;
  } else {
    int e = fexp(mx); float sc = p2(-e);
    #pragma unroll
    for (int i = 0; i < 8; ++i) wp[b * 8 + i] = v[i] * sc;
    EWc[ltask * 8 + b] = ec + e;
  }
}

// K3b: combine (levels A/B/C) + fp64 replay + log, fused in one 128-thread
// block. bounds(128,1) -> no VGPR cap issues. Cs/Eacc handed off in LDS.
__global__ __launch_bounds__(128, 1) void k_fin(const float* __restrict__ M,
        const float* __restrict__ Wt, const int* __restrict__ EWc,
        float* __restrict__ Pm, float* __restrict__ aL, float* __restrict__ bL) {
  __shared__ float sWt[128][68];
  __shared__ int   sEW[128 * 8];
  __shared__ int   sEP[128 * 8];
  __shared__ float Gm[16 * 69];
  __shared__ float Sg[16 * 9];
  __shared__ int   EGs[16 * 8];
  __shared__ int   EsB[16];
  __shared__ float sCs[128 * 8];
  __shared__ int   sEacc[128];
  const int tid = threadIdx.x;
  const float4* Mv = (const float4*)M;

  for (int i = tid; i < 128 * 16; i += 128) {
    int task = i >> 4, q = i & 15;
    float4 v4 = ((const float4*)Wt)[i];
    *(float4*)&sWt[task][q * 4] = v4;
  }
  for (int i = tid; i < 1024; i += 128) sEW[i] = EWc[i];
  __syncthreads();

  // level A: basis through each group of 8 chunks (16 tasks x 8 basis lanes)
  {
    const int dir = tid >> 6, w = (tid >> 3) & 7, b = tid & 7;
    float v[8];
    #pragma unroll
    for (int i = 0; i < 8; ++i) v[i] = (i == b) ? 1.f : 0.f;
    int ec = 0;
    for (int c = 0; c < 8; ++c) {
      int lc = w * 8 + c, lt = dir * 64 + lc;
      float* pp = Pm + lt * 64 + b * 8;
      #pragma unroll
      for (int i = 0; i < 8; ++i) pp[i] = v[i];
      sEP[lt * 8 + b] = ec;
      const float* wp = &sWt[lt][0];
      int ew[8];
      #pragma unroll
      for (int j = 0; j < 8; ++j) ew[j] = sEW[lt * 8 + j];
      int emax = ew[0];
      #pragma unroll
      for (int j = 1; j < 8; ++j) emax = max(emax, ew[j]);
      float nv[8] = {0, 0, 0, 0, 0, 0, 0, 0};
      #pragma unroll
      for (int j = 0; j < 8; ++j) {
        float tj = v[j] * p2c(ew[j] - emax + 64);
        float4 ca = *(const float4*)(wp + j * 8);
        float4 cb = *(const float4*)(wp + j * 8 + 4);
        nv[0] = fmaf(tj, ca.x, nv[0]); nv[1] = fmaf(tj, ca.y, nv[1]);
        nv[2] = fmaf(tj, ca.z, nv[2]); nv[3] = fmaf(tj, ca.w, nv[3]);
        nv[4] = fmaf(tj, cb.x, nv[4]); nv[5] = fmaf(tj, cb.y, nv[5]);
        nv[6] = fmaf(tj, cb.z, nv[6]); nv[7] = fmaf(tj, cb.w, nv[7]);
      }
      float mx = 0.f;
      #pragma unroll
      for (int i = 0; i < 8; ++i) mx = fmaxf(mx, nv[i]);
      if (fexpbits(mx) == 0) {
        #pragma unroll
        for (int i = 0; i < 8; ++i) v[i] = 0.f;
        ec = NEGE;
      } else {
        int e = fexp(mx); float sc = p2(-e);
        #pragma unroll
        for (int i = 0; i < 8; ++i) v[i] = nv[i] * sc;
        ec = ec + emax + e - 64;
      }
    }
    float* gp = Gm + (dir * 8 + w) * 69 + b * 8;
    #pragma unroll
    for (int i = 0; i < 8; ++i) gp[i] = v[i];
    EGs[(dir * 8 + w) * 8 + b] = ec;
  }
  __syncthreads();

  // level B: sequential over 8 groups (8 lanes per dir)
  if (tid < 8 || (tid >= 64 && tid < 72)) {
    const int dir = (tid >= 64) ? 1 : 0, j = tid & 7;
    float s[8];
    #pragma unroll
    for (int i = 0; i < 8; ++i) s[i] = (i == 0) ? 1.f : 0.f;
    int Es = 0;
    for (int w = 0; w < 8; ++w) {
      float sj = s[0];
      #pragma unroll
      for (int i = 1; i < 8; ++i) if (j == i) sj = s[i];
      Sg[(dir * 8 + w) * 9 + j] = sj;
      if (j == 0) EsB[dir * 8 + w] = Es;
      int eg[8];
      #pragma unroll
      for (int i = 0; i < 8; ++i) eg[i] = EGs[(dir * 8 + w) * 8 + i];
      int egmax = eg[0];
      #pragma unroll
      for (int i = 1; i < 8; ++i) egmax = max(egmax, eg[i]);
      int egj = eg[0];
      #pragma unroll
      for (int i = 1; i < 8; ++i) if (j == i) egj = eg[i];
      float tb = sj * p2c(egj - egmax + 64);
      const float* gp = Gm + (dir * 8 + w) * 69 + j * 8;
      float p[8];
      #pragma unroll
      for (int i = 0; i < 8; ++i) p[i] = gp[i] * tb;
      #pragma unroll
      for (int m = 1; m <= 4; m <<= 1)
        #pragma unroll
        for (int i = 0; i < 8; ++i) p[i] += __shfl_xor(p[i], m);
      float mx = 0.f;
      #pragma unroll
      for (int i = 0; i < 8; ++i) mx = fmaxf(mx, p[i]);
      int e = fexp(mx); float sc = p2(-e);
      #pragma unroll
      for (int i = 0; i < 8; ++i) s[i] = p[i] * sc;
      Es += egmax + e - 64;
    }
  }
  __syncthreads();

  // level C: chunk-start vectors, written to LDS in PHYSICAL chunk order
  {
    const int dir = tid >> 6, lc = tid & 63, w = lc >> 3;
    float sg[8];
    #pragma unroll
    for (int b = 0; b < 8; ++b) sg[b] = Sg[(dir * 8 + w) * 9 + b];
    int Es = EsB[dir * 8 + w];
    int ep[8];
    #pragma unroll
    for (int b = 0; b < 8; ++b) ep[b] = sEP[(dir * 64 + lc) * 8 + b];
    int epmax = ep[0];
    #pragma unroll
    for (int b = 1; b < 8; ++b) epmax = max(epmax, ep[b]);
    float cs[8] = {0, 0, 0, 0, 0, 0, 0, 0};
    #pragma unroll
    for (int b = 0; b < 8; ++b) {
      float coef = sg[b] * p2c(ep[b] - epmax + 64);
      const float* pp = Pm + (dir * 64 + lc) * 64 + b * 8;
      float4 ca = *(const float4*)pp;
      float4 cb = *(const float4*)(pp + 4);
      cs[0] = fmaf(coef, ca.x, cs[0]); cs[1] = fmaf(coef, ca.y, cs[1]);
      cs[2] = fmaf(coef, ca.z, cs[2]); cs[3] = fmaf(coef, ca.w, cs[3]);
      cs[4] = fmaf(coef, cb.x, cs[4]); cs[5] = fmaf(coef, cb.y, cs[5]);
      cs[6] = fmaf(coef, cb.z, cs[6]); cs[7] = fmaf(coef, cb.w, cs[7]);
    }
    float mx = 0.f;
    #pragma unroll
    for (int i = 0; i < 8; ++i) mx = fmaxf(mx, cs[i]);
    int phys = dir ? (63 - lc) : lc;
    float* cp = &sCs[(dir * 64 + phys) * 8];
    if (fexpbits(mx) == 0) {
      #pragma unroll
      for (int i = 0; i < 8; ++i) cp[i] = 0.f;
      sEacc[dir * 64 + phys] = NEGE;
    } else {
      int e = fexp(mx); float sc = p2(-e);
      #pragma unroll
      for (int i = 0; i < 8; ++i) cp[i] = cs[i] * sc;
      sEacc[dir * 64 + phys] = Es + epmax + e - 64;
    }
  }
  __syncthreads();

  // fp64 replay per chunk, fused with log -> aL/bL (verbatim R4 k_replay)
  {
    const int dir = tid >> 6;
    const int c = tid & 63;
    const int base = c * KCH;
    const float* cp = &sCs[(dir * 64 + c) * 8];
    double st[8];
    #pragma unroll
    for (int i = 0; i < 8; ++i) st[i] = (double)cp[i];
    const double eacc = (double)sEacc[dir * 64 + c];
    if (tid == 0) { aL[0] = 0.f; bL[TT] = 0.f; }
    if (dir == 0) {
      float4 ra = Mv[base * 2], rb = Mv[base * 2 + 1];
      for (int kg = 0; kg < 4; ++kg) {
        #pragma unroll
        for (int kk = 0; kk < 8; ++kk) {
          int k = kg * 8 + kk;
          float4 c0 = ra, c1 = rb;
          int nk = (k + 1 < KCH) ? k + 1 : KCH - 1;
          ra = Mv[(base + nk) * 2]; rb = Mv[(base + nk) * 2 + 1];
          double a_ = st[kk & 7];
          st[(kk + 1) & 7] = fma(a_, (double)c0.x, st[(kk + 1) & 7]);
          st[(kk + 2) & 7] = fma(a_, (double)c0.y, st[(kk + 2) & 7]);
          st[(kk + 3) & 7] = fma(a_, (double)c0.z, st[(kk + 3) & 7]);
          st[(kk + 4) & 7] = fma(a_, (double)c0.w, st[(kk + 4) & 7]);
          st[(kk + 5) & 7] = fma(a_, (double)c1.x, st[(kk + 5) & 7]);
          st[(kk + 6) & 7] = fma(a_, (double)c1.y, st[(kk + 6) & 7]);
          st[(kk + 7) & 7] = fma(a_, (double)c1.z, st[(kk + 7) & 7]);
          st[kk & 7]       = a_ * (double)c1.w;
          double val = st[(kk + 1) & 7];
          long long bits = __double_as_longlong(val);
          int e2 = (int)((bits >> 52) & 0x7ff) - 1023;
          double mant = __longlong_as_double((bits & 0xFFFFFFFFFFFFFLL) | 0x3FF0000000000000LL);
          float lg = log2f((float)mant);
          aL[base + k + 1] = (float)(((double)e2 + eacc + (double)lg) * LN2D);
        }
      }
    } else {
      float4 ra = Mv[(base + KCH - 1) * 2], rb = Mv[(base + KCH - 1) * 2 + 1];
      for (int kg = 0; kg < 4; ++kg) {
        #pragma unroll
        for (int kk = 0; kk < 8; ++kk) {
          int k = kg * 8 + kk;
          int t = base + KCH - 1 - k;
          float4 c0 = ra, c1 = rb;
          int nk = (k + 1 < KCH) ? k + 1 : KCH - 1;
          int nt = base + KCH - 1 - nk;
          ra = Mv[nt * 2]; rb = Mv[nt * 2 + 1];
          double nb =            (double)c0.x * st[(8  - kk) & 7];
          nb = fma((double)c0.y, st[(9  - kk) & 7], nb);
          nb = fma((double)c0.z, st[(10 - kk) & 7], nb);
          nb = fma((double)c0.w, st[(11 - kk) & 7], nb);
          nb = fma((double)c1.x, st[(12 - kk) & 7], nb);
          nb = fma((double)c1.y, st[(13 - kk) & 7], nb);
          nb = fma((double)c1.z, st[(14 - kk) & 7], nb);
          nb = fma((double)c1.w, st[(15 - kk) & 7], nb);
          st[(7 - kk) & 7] = nb;
          long long bits = __double_as_longlong(nb);
          int e2 = (int)((bits >> 52) & 0x7ff) - 1023;
          double mant = __longlong_as_double((bits & 0xFFFFFFFFFFFFFLL) | 0x3FF0000000000000LL);
          float lg = log2f((float)mant);
          bL[t] = (float)(((double)e2 + eacc + (double)lg) * LN2D);
        }
      }
    }
  }
}

// K4: dense output.
__global__ void k_out(const PK* __restrict__ pk, const unsigned long long* __restrict__ w64,
                      const float* __restrict__ aL, const float* __restrict__ bL,
                      float* __restrict__ out, int T, int V, int tPer) {
  int v = blockIdx.x * blockDim.x + threadIdx.x;
  PK p = pk[v];
  unsigned long long mask = (p.len >= 8) ? ~0ull : ((1ull << (8 * p.len)) - 1ull);
  unsigned long long key = p.key;
  float norm = aL[T];
  float base = p.logp - norm;
  int t0 = blockIdx.y * tPer;
  for (int t = t0; t < t0 + tPer; ++t) {
    unsigned long long w = w64[t];
    float val = 0.f;
    if (((w ^ key) & mask) == 0ull)
      val = __expf(aL[t] + base + bL[t + p.len]);
    out[(size_t)t * V + v] = val;
  }
}

extern "C" void kernel_launch(void* const* d_in, const int* in_sizes, int n_in,
                              void* d_out, int out_size, void* d_ws, size_t ws_size,
                              hipStream_t stream) {
  const int* seq    = (const int*)d_in[0];
  const int* pieces = (const int*)d_in[1];
  const int* plens  = (const int*)d_in[2];
  const float* logp = (const float*)d_in[3];
  float* out = (float*)d_out;
  const int T = in_sizes[0];
  const int V = in_sizes[2];

  char* p = (char*)d_ws;
  PK* pk = (PK*)p;                                   p += (size_t)V * sizeof(PK);
  unsigned long long* w64 = (unsigned long long*)p;  p += (size_t)T * 8;
  float* M = (float*)p;                              p += (size_t)T * LMAX * 4;
  float* Wt = (float*)p;                             p += (size_t)128 * 64 * 4;
  int* EWc = (int*)p;                                p += (size_t)128 * 8 * 4;
  float* Pm = (float*)p;                             p += (size_t)128 * 64 * 4;
  float* aL = (float*)p;                             p += 8208;
  float* bL = (float*)p;                             p += 8208;

  int prepN = V + T + T * LMAX;
  k_prep<<<(prepN + 255) / 256, 256, 0, stream>>>(seq, pieces, plens, logp, pk, w64, M, T, V);

  const int tPer2 = 128;
  dim3 g2(V / 256, T / tPer2);
  k_match<<<g2, 256, 0, stream>>>(pk, w64, M, T, V, tPer2);

  k_chunks<<<16, 64, 0, stream>>>(M, Wt, EWc);
  k_fin<<<1, 128, 0, stream>>>(M, Wt, EWc, Pm, aL, bL);

  const int tPer5 = 32;
  dim3 g5(V / 256, T / tPer5);
  k_out<<<g5, 256, 0, stream>>>(pk, w64, aL, bL, out, T, V, tPer5);
}